// Round 11
// baseline (148.583 us; speedup 1.0000x reference)
//
#include <hip/hip_runtime.h>

// N=512, D=512 pairwise scorer, all f32 in/out.
// left = E@W1[:D]; right = E@W1[D:]+b1; h = left[i]+right[j]; LN(D); GELU; @W2+b2; sigmoid.
// LN stats decompose (raw-moment): mu_h = mu_l+mu_r; var_h = var_l+var_r+2cov;
// cov = dot(l,r)/D - mu_l*mu_r. Never materialize [N,N,D].
// W (left/right activations) stored bf16: halves staging bytes; error budget
// ~7e-3 << 1.94e-2 threshold. k_pair: 40KB LDS -> 4 blocks/CU (occupancy fix).
// k_gemm: explicit ping-pong load batches (round 10: compiler minimized to
// 32 VGPR and serialized loads -> 9% VALUBusy); launch_bounds(256,2) relaxes
// the register target (kernel needs ~90, cap 256 -- NOT round-7 over-cap).

#define N_ 512
#define D_ 512
#define LSTR 520   // ushort row stride: 1040 B = 16-aligned; 260 words = 4 mod 32
                   // -> all hot LDS reads <=2-way (free); checked per-phase.

typedef unsigned short bfraw;

__device__ __forceinline__ bfraw f2bf(float f) {
    union { float f; unsigned u; } v; v.f = f;
    return (bfraw)((v.u + 0x7FFFu + ((v.u >> 16) & 1u)) >> 16);
}
__device__ __forceinline__ float bfl(unsigned u) {
    union { unsigned i; float f; } v; v.i = u << 16; return v.f;
}
__device__ __forceinline__ float bfh(unsigned u) {
    union { unsigned i; float f; } v; v.i = u & 0xffff0000u; return v.f;
}
__device__ __forceinline__ float4 up4(uint2 u) {
    float4 f; f.x = bfl(u.x); f.y = bfh(u.x); f.z = bfl(u.y); f.w = bfh(u.y);
    return f;
}

// ---------------- K1: left/right GEMMs -> bf16 W ----------------
// 512 blocks = 64 rowgrps (8 rows) x 8 ccgrps (128 combined cols of 1024).
// 256 thr: col quad = t&31, row = t>>5. Ping-pong batches of 8 dwordx4 keep
// 8 loads in flight while 32 FMAs retire. W1 L2 traffic 128 MB (~5us floor).
#define FMA8(W_, ee) \
    acc.x = fmaf(ee, W_.x, acc.x); acc.y = fmaf(ee, W_.y, acc.y); \
    acc.z = fmaf(ee, W_.z, acc.z); acc.w = fmaf(ee, W_.w, acc.w);

__global__ __launch_bounds__(256, 2) void k_gemm(const float* __restrict__ E,
                                                 const float* __restrict__ W1,
                                                 const float* __restrict__ b1,
                                                 bfraw* __restrict__ Wb /* [1024][512] bf16 */) {
    __shared__ float e[8 * 516];
    const int t = threadIdx.x;
    const int cc = (blockIdx.x & 7) * 128;
    const int r0 = (blockIdx.x >> 3) * 8;
    const int half = cc >> 9;
    const int c = (cc & 511) + (t & 31) * 4;
    const int r = t >> 5;

#pragma unroll
    for (int it = 0; it < 4; ++it) {
        int x = t + it * 256;
        int rr = x >> 7, q = x & 127;
        *(float4*)&e[rr * 516 + q * 4] = *(const float4*)&E[(r0 + rr) * D_ + q * 4];
    }
    __syncthreads();

    const float* __restrict__ wp = W1 + (half << 18) + c;
    const float* __restrict__ ep = e + r * 516;
    float4 acc = {0.f, 0.f, 0.f, 0.f};
    float4 wa[8], wb[8];
#pragma unroll
    for (int j = 0; j < 8; ++j) wa[j] = *(const float4*)(wp + (j << 9));
    for (int kb = 0; kb < 512; kb += 16) {
#pragma unroll
        for (int j = 0; j < 8; ++j) wb[j] = *(const float4*)(wp + ((kb + 8 + j) << 9));
        float4 ea = *(const float4*)(ep + kb);
        float4 eb = *(const float4*)(ep + kb + 4);
        FMA8(wa[0], ea.x); FMA8(wa[1], ea.y); FMA8(wa[2], ea.z); FMA8(wa[3], ea.w);
        FMA8(wa[4], eb.x); FMA8(wa[5], eb.y); FMA8(wa[6], eb.z); FMA8(wa[7], eb.w);
        if (kb + 16 < 512) {
#pragma unroll
            for (int j = 0; j < 8; ++j) wa[j] = *(const float4*)(wp + ((kb + 16 + j) << 9));
        }
        float4 ec = *(const float4*)(ep + kb + 8);
        float4 ed = *(const float4*)(ep + kb + 12);
        FMA8(wb[0], ec.x); FMA8(wb[1], ec.y); FMA8(wb[2], ec.z); FMA8(wb[3], ec.w);
        FMA8(wb[4], ed.x); FMA8(wb[5], ed.y); FMA8(wb[6], ed.z); FMA8(wb[7], ed.w);
    }
    if (half) {
        float4 bb = *(const float4*)(b1 + c);
        acc.x += bb.x; acc.y += bb.y; acc.z += bb.z; acc.w += bb.w;
    }
    ushort4 o;
    o.x = f2bf(acc.x); o.y = f2bf(acc.y); o.z = f2bf(acc.z); o.w = f2bf(acc.w);
    *(ushort4*)&Wb[((half << 9) + r0 + r) * D_ + c] = o;
}

// ------- K2: fused stats -> cov -> rstd -> gelu-dot -> sigmoid -------
// 528 blocks = upper-triangle 16x16 pair tiles. 256 thr:
//   lane l = t&63: pt = l&15 (4x4 pair block), s = l>>4; sigma = (t>>6)*4+s
//   owns k-quads {16m+sigma}, m=0..7. bf16 tiles staged once (33 KB) ->
//   total ~40KB LDS -> 4 blocks/CU; VGPR ~124 -> 4 waves/SIMD. Balanced.
__device__ __forceinline__ void gelu_acc(float l, float r, float g, float be,
                                         float w, float rstd, float m2, float& acc) {
    // u = (l+r-mu)*rstd = fma(l+r, rstd, m2); gelu via sigmoid form;
    // q = log2(exp(-2y)) = x*(A*x^2+B), B = -2*log2e*0.79788456, A = B*0.044715
    float s = l + r;
    float u = fmaf(s, rstd, m2);
    float x = fmaf(u, g, be);
    float x2 = x * x;
    float q = x * fmaf(-0.10294340f, x2, -2.30220935f);
    float eq = __builtin_amdgcn_exp2f(q);
    float ge = x * __builtin_amdgcn_rcpf(1.f + eq);
    acc = fmaf(ge, w, acc);
}

__global__ __launch_bounds__(256) void k_pair(const bfraw* __restrict__ Wb,
                                              const float* __restrict__ gf,
                                              const float* __restrict__ bef,
                                              const float* __restrict__ wf,
                                              const float* __restrict__ b2,
                                              float* __restrict__ out) {
    __shared__ bfraw ls[16 * LSTR];
    __shared__ bfraw rs[16 * LSTR];
    __shared__ float red4[4 * 272];     // [wv][pt*17 + c]
    __shared__ float mu_s[32], vv_s[32];
    __shared__ float rstd_s[256], m2_s[256];

    // decode upper-triangle tile index b -> (I, J), I<=J, 32 tile-rows
    const int b = blockIdx.x;
    int I = (int)((65.0f - sqrtf(4225.0f - 8.0f * (float)b)) * 0.5f);
    if (I < 0) I = 0;
    if (I > 31) I = 31;
#define S_(i) (32 * (i) - ((i) * ((i)-1)) / 2)
    while (S_(I) > b) --I;
    while (S_(I + 1) <= b) ++I;
    const int J = I + (b - S_(I));
#undef S_

    const int t = threadIdx.x;
    const int l = t & 63, wv = t >> 6;
    const int pt = l & 15, s = l >> 4;
    const int sigma = wv * 4 + s;
    const int i4 = (pt & 3) * 4, j4 = (pt >> 2) * 4;
    const int Ibase = I * 16, Jbase = N_ + J * 16;

    // ---- stage bf16 tiles once: 16 rows x 64 uint4-chunks each ----
#pragma unroll
    for (int it = 0; it < 4; ++it) {
        int x = t + it * 256;
        int rr = x >> 6, ch = x & 63;
        *(uint4*)&ls[rr * LSTR + ch * 8] = *(const uint4*)&Wb[(Ibase + rr) * D_ + ch * 8];
        *(uint4*)&rs[rr * LSTR + ch * 8] = *(const uint4*)&Wb[(Jbase + rr) * D_ + ch * 8];
    }
    __syncthreads();

    // ---- per-row stats: row = t>>3 (0..31), q = t&7; 8 chunks of 8 elems ----
    {
        const int row = t >> 3, q = t & 7;
        const bfraw* src = (row < 16) ? &ls[row * LSTR] : &rs[(row - 16) * LSTR];
        float sum = 0.f, ss = 0.f;
#pragma unroll
        for (int j = 0; j < 8; ++j) {
            uint4 u = *(const uint4*)&src[(j * 8 + q) * 8];
            float4 a = up4(make_uint2(u.x, u.y));
            float4 bq = up4(make_uint2(u.z, u.w));
            sum += a.x + a.y + a.z + a.w + bq.x + bq.y + bq.z + bq.w;
            ss += a.x * a.x + a.y * a.y + a.z * a.z + a.w * a.w +
                  bq.x * bq.x + bq.y * bq.y + bq.z * bq.z + bq.w * bq.w;
        }
#pragma unroll
        for (int off = 1; off < 8; off <<= 1) {
            sum += __shfl_xor(sum, off, 64);
            ss += __shfl_xor(ss, off, 64);
        }
        if (q == 0) {
            float mu = sum * (1.f / D_);
            mu_s[row] = mu;
            vv_s[row] = ss * (1.f / D_) - mu * mu;
        }
    }
    // ---- pass A: raw dot partials (4x4, this sigma's 32 k) ----
    float cv[16];
#pragma unroll
    for (int c = 0; c < 16; ++c) cv[c] = 0.f;
#pragma unroll
    for (int mm = 0; mm < 8; ++mm) {
        const int off = 64 * mm + 4 * sigma;   // ushort offset
        float4 lq[4], rq[4];
#pragma unroll
        for (int d = 0; d < 4; ++d) {
            lq[d] = up4(*(const uint2*)&ls[(i4 + d) * LSTR + off]);
            rq[d] = up4(*(const uint2*)&rs[(j4 + d) * LSTR + off]);
        }
#pragma unroll
        for (int di = 0; di < 4; ++di)
#pragma unroll
            for (int dj = 0; dj < 4; ++dj)
                cv[di * 4 + dj] += lq[di].x * rq[dj].x + lq[di].y * rq[dj].y +
                                   lq[di].z * rq[dj].z + lq[di].w * rq[dj].w;
    }
#pragma unroll
    for (int c = 0; c < 16; ++c) {
        cv[c] += __shfl_xor(cv[c], 16, 64);
        cv[c] += __shfl_xor(cv[c], 32, 64);
    }
    if (l < 16) {
#pragma unroll
        for (int c = 0; c < 16; ++c) red4[wv * 272 + pt * 17 + c] = cv[c];
    }
    __syncthreads();

    // ---- per-pair rstd/m2: thread t = (ii = t&15, jj = t>>4) ----
    {
        const int ii = t & 15, jj = t >> 4;
        const int ppt = (ii >> 2) + ((jj >> 2) << 2);
        const int cc2 = (ii & 3) * 4 + (jj & 3);
        float dot = red4[0 * 272 + ppt * 17 + cc2] + red4[1 * 272 + ppt * 17 + cc2] +
                    red4[2 * 272 + ppt * 17 + cc2] + red4[3 * 272 + ppt * 17 + cc2];
        float mui = mu_s[ii], muj = mu_s[16 + jj];
        float cov = dot * (1.f / D_) - mui * muj;
        float varh = vv_s[ii] + vv_s[16 + jj] + 2.f * cov + 1e-5f;
        float rstd = rsqrtf(varh);
        rstd_s[t] = rstd;
        m2_s[t] = -(mui + muj) * rstd;
    }
    __syncthreads();

    // ---- pass B: gelu dot ----
    float rstA[16], m2A[16];
#pragma unroll
    for (int di = 0; di < 4; ++di)
#pragma unroll
        for (int dj = 0; dj < 4; ++dj) {
            int p = (j4 + dj) * 16 + (i4 + di);
            rstA[di * 4 + dj] = rstd_s[p];
            m2A[di * 4 + dj] = m2_s[p];
        }
    float ac[16];
#pragma unroll
    for (int c = 0; c < 16; ++c) ac[c] = 0.f;
#pragma unroll 2
    for (int mm = 0; mm < 8; ++mm) {
        const int off = 64 * mm + 4 * sigma;
        float4 g4 = *(const float4*)&gf[off];
        float4 be4 = *(const float4*)&bef[off];
        float4 w4 = *(const float4*)&wf[off];
        float4 lq[4], rq[4];
#pragma unroll
        for (int d = 0; d < 4; ++d) {
            lq[d] = up4(*(const uint2*)&ls[(i4 + d) * LSTR + off]);
            rq[d] = up4(*(const uint2*)&rs[(j4 + d) * LSTR + off]);
        }
#pragma unroll
        for (int di = 0; di < 4; ++di)
#pragma unroll
            for (int dj = 0; dj < 4; ++dj) {
                float rr2 = rstA[di * 4 + dj], mm2 = m2A[di * 4 + dj];
                float& a = ac[di * 4 + dj];
                gelu_acc(lq[di].x, rq[dj].x, g4.x, be4.x, w4.x, rr2, mm2, a);
                gelu_acc(lq[di].y, rq[dj].y, g4.y, be4.y, w4.y, rr2, mm2, a);
                gelu_acc(lq[di].z, rq[dj].z, g4.z, be4.z, w4.z, rr2, mm2, a);
                gelu_acc(lq[di].w, rq[dj].w, g4.w, be4.w, w4.w, rr2, mm2, a);
            }
    }
#pragma unroll
    for (int c = 0; c < 16; ++c) {
        ac[c] += __shfl_xor(ac[c], 16, 64);
        ac[c] += __shfl_xor(ac[c], 32, 64);
    }
    __syncthreads();   // red4 reuse
    if (l < 16) {
#pragma unroll
        for (int c = 0; c < 16; ++c) red4[wv * 272 + pt * 17 + c] = ac[c];
    }
    __syncthreads();

    {   // finalize: thread t = pair (ii, jj)
        const int ii = t & 15, jj = t >> 4;
        const int ppt = (ii >> 2) + ((jj >> 2) << 2);
        const int cc2 = (ii & 3) * 4 + (jj & 3);
        float z = red4[0 * 272 + ppt * 17 + cc2] + red4[1 * 272 + ppt * 17 + cc2] +
                  red4[2 * 272 + ppt * 17 + cc2] + red4[3 * 272 + ppt * 17 + cc2] + b2[0];
        float sg = __builtin_amdgcn_rcpf(1.f + __builtin_amdgcn_exp2f(-1.44269504f * z));
        const int gi = Ibase + ii, gj = J * 16 + jj;
        if (gi <= gj) {
            out[gi * N_ + gj] = sg;
            out[gj * N_ + gi] = sg;
        }
    }
}

extern "C" void kernel_launch(void* const* d_in, const int* in_sizes, int n_in,
                              void* d_out, int out_size, void* d_ws, size_t ws_size,
                              hipStream_t stream) {
    const float* E     = (const float*)d_in[0];
    const float* W1    = (const float*)d_in[1];
    const float* b1    = (const float*)d_in[2];
    const float* gamma = (const float*)d_in[3];
    const float* beta  = (const float*)d_in[4];
    const float* w2    = (const float*)d_in[5];
    const float* b2    = (const float*)d_in[6];
    float* out = (float*)d_out;

    bfraw* Wb = (bfraw*)d_ws;  // [1024][512] bf16: rows 0..511 left, 512..1023 right+b1

    k_gemm<<<512, 256, 0, stream>>>(E, W1, b1, Wb);
    k_pair<<<528, 256, 0, stream>>>(Wb, gamma, beta, w2, b2, out);
}